// Round 1
// baseline (257.415 us; speedup 1.0000x reference)
//
#include <hip/hip_runtime.h>
#include <math.h>

#define MAXN 0.996f  /* (1-PROJ_EPS)/sqrt(c) */

__device__ __forceinline__ float wredsum(float v) {
#pragma unroll
  for (int o = 32; o > 0; o >>= 1) v += __shfl_xor(v, o);
  return v;
}

__device__ __forceinline__ float artanh_f(float x) {
  x = fminf(fmaxf(x, -1.0f + 1e-7f), 1.0f - 1e-7f);
  return 0.5f * (log1pf(x) - log1pf(-x));
}

// per-row sum of x[N,128] -> s[N]
__global__ void k_rowsum(const float* __restrict__ x, float* __restrict__ s) {
  const int row = blockIdx.x, j = threadIdx.x;  // 64 threads
  float a = x[(size_t)row * 128 + j] + x[(size_t)row * 128 + 64 + j];
  a = wredsum(a);
  if (j == 0) s[row] = a;
}

// scatter edge weights into block-diagonal adj1 [32][256][256]
__global__ void k_edges(const int* __restrict__ er, const int* __restrict__ ec,
                        const float* __restrict__ s, float* __restrict__ adj, int nE) {
  int e = blockIdx.x * blockDim.x + threadIdx.x;
  if (e >= nE) return;
  int r = er[e], c = ec[e];
  int g = r >> 8;
  adj[(((size_t)g * 256) + (r & 255)) * 256 + (c & 255)] = 0.5f * (s[r] + s[c]);
}

// HypLinear + hyperbolic bias + logmap0:  u = logmap0(proj(mobius_add(proj(mobius_matvec(W, to_hyp_row)), hb)))
// one 64-lane wave per row; IND = input dim (128 or 64); output dim 64
template <int IND>
__global__ void k_stageA(const float* __restrict__ x, const float* __restrict__ Wm,
                         const float* __restrict__ b, float* __restrict__ u) {
  const int row = blockIdx.x;
  const int j = threadIdx.x;  // 64
  __shared__ float xs[IND];
  for (int t = j; t < IND; t += 64) xs[t] = x[(size_t)row * IND + t];
  __syncthreads();

  // hb = proj(expmap0(b))   (recomputed per block; cheap)
  float bj = b[j];
  float nb = sqrtf(wredsum(bj * bj));
  float ub = fmaxf(nb, 1e-15f);
  float eb = tanhf(ub) / ub;
  float cb = fmaxf(eb * nb, 1e-15f);
  float hbj = bj * eb * ((cb > MAXN) ? MAXN / cb : 1.0f);
  float y2 = wredsum(hbj * hbj);

  // xh = proj(expmap0(x_row)) = alpha * x_row
  float a2 = 0.f;
  for (int t = j; t < IND; t += 64) a2 += xs[t] * xs[t];
  float nx = sqrtf(wredsum(a2));
  float un = fmaxf(nx, 1e-15f);
  float s1 = tanhf(un) / un;
  float nv = s1 * nx;                // norm after expmap0
  float nn = fmaxf(nv, 1e-15f);
  float s2 = (nn > MAXN) ? MAXN / nn : 1.0f;
  float alpha = s1 * s2;
  float xn = fmaxf(fminf(nn, MAXN), 1e-15f);  // _norm(xh)

  // mx = xh @ W.T
  float y = 0.f;
  const float* wr = Wm + (size_t)j * IND;
  for (int t = 0; t < IND; ++t) y += xs[t] * wr[t];
  float mxj = alpha * y;
  float mxn = fmaxf(sqrtf(wredsum(mxj * mxj)), 1e-15f);
  float hj = (tanhf(mxn / xn * artanh_f(xn)) / mxn) * mxj;

  // proj
  float hn = fmaxf(sqrtf(wredsum(hj * hj)), 1e-15f);
  if (hn > MAXN) hj *= MAXN / hn;

  // mobius_add(h, hb)
  float x2 = wredsum(hj * hj);
  float xy = wredsum(hj * hbj);
  float num = (1.f + 2.f * xy + y2) * hj + (1.f - x2) * hbj;
  float den = fmaxf(1.f + 2.f * xy + x2 * y2, 1e-15f);
  float aj = num / den;

  // proj + logmap0
  float an = fmaxf(sqrtf(wredsum(aj * aj)), 1e-15f);
  float pn = an;
  if (an > MAXN) { aj *= MAXN / an; pn = MAXN; }
  u[(size_t)row * 64 + j] = (artanh_f(pn) / pn) * aj;
}

// HypAgg + HypAct + logmap0 (+ optional deg->dis for the pool):
// t_row = logmap0(proj(expmap0(relu(logmap0(proj(expmap0( (adj @ u)_row )))))))
template <int NPGL>
__global__ void k_stageB(const float* __restrict__ adj, const float* __restrict__ u,
                         float* __restrict__ t, float* __restrict__ dis, int wantDis) {
  const int row = blockIdx.x;
  const int g = row / NPGL;
  const int j = threadIdx.x;  // 64
  const float* arow = adj + (size_t)row * NPGL;
  const float* ug = u + (size_t)g * NPGL * 64;
  float acc = 0.f, dsum = 0.f;
  for (int c = 0; c < NPGL; ++c) { float a = arow[c]; acc += a * ug[(size_t)c * 64 + j]; dsum += a; }

  float n0 = sqrtf(wredsum(acc * acc));
  float u0 = fmaxf(n0, 1e-15f);
  float e1 = tanhf(u0) / u0;
  float c1 = fmaxf(e1 * n0, 1e-15f);
  float v = acc * e1;
  if (c1 > MAXN) { v *= MAXN / c1; c1 = MAXN; }
  v *= artanh_f(c1) / c1;   // logmap0
  v = fmaxf(v, 0.f);        // relu in tangent space

  float n2 = sqrtf(wredsum(v * v));
  float u2 = fmaxf(n2, 1e-15f);
  float e2 = tanhf(u2) / u2;
  float c2 = fmaxf(e2 * n2, 1e-15f);
  v *= e2;
  if (c2 > MAXN) { v *= MAXN / c2; c2 = MAXN; }
  v *= artanh_f(c2) / c2;   // final logmap0
  t[(size_t)row * 64 + j] = v;
  if (wantDis && j == 0) dis[row] = (dsum > 0.f) ? (1.0f / sqrtf(dsum)) : 0.f;
}

// node information score: score_i = sum_j | t_ij - dis_i * sum_c adj_ic * dis_c * t_cj |
template <int NPGL>
__global__ void k_stageC(const float* __restrict__ adj, const float* __restrict__ t,
                         const float* __restrict__ dis, float* __restrict__ score) {
  const int row = blockIdx.x;
  const int g = row / NPGL;
  const int j = threadIdx.x;  // 64
  const float* arow = adj + (size_t)row * NPGL;
  const float* tg = t + (size_t)g * NPGL * 64;
  const float* dg = dis + (size_t)g * NPGL;
  float acc = 0.f;
  for (int c = 0; c < NPGL; ++c) acc += arow[c] * dg[c] * tg[(size_t)c * 64 + j];
  float d = fabsf(t[(size_t)row * 64 + j] - dis[row] * acc);
  d = wredsum(d);
  if (j == 0) score[row] = d;
}

// per-graph exact top-k (jax tie-break: lower index first) + xn = t[sel]*tanh(val)
// + attention projections s1,s2 + graph readout (max|mean over k rows)
template <int NPGL>
__global__ void k_stageD(const float* __restrict__ score, const float* __restrict__ t,
                         const float* __restrict__ att, float* __restrict__ xn,
                         float* __restrict__ s1o, float* __restrict__ s2o,
                         int* __restrict__ gidx, float* __restrict__ xread) {
  constexpr int K = NPGL / 2;
  const int g = blockIdx.x;
  const int i = threadIdx.x;  // NPGL threads
  __shared__ float sc[NPGL];
  __shared__ int sel[K];
  __shared__ float sval[K];
  __shared__ float xs[K * 64];
  sc[i] = score[(size_t)g * NPGL + i];
  __syncthreads();
  float si = sc[i];
  int rank = 0;
  for (int c = 0; c < NPGL; ++c) { float v = sc[c]; rank += (v > si) || (v == si && c < i); }
  if (rank < K) { sel[rank] = i; sval[rank] = si; }
  __syncthreads();
  if (i < K) {
    int li = sel[i];
    float tv = tanhf(sval[i]);
    const float* trow = t + ((size_t)g * NPGL + li) * 64;
    float a = 0.f, b = 0.f;
    for (int jj = 0; jj < 64; ++jj) {
      float v = trow[jj] * tv;
      xs[i * 64 + jj] = v;
      a += v * att[jj];
      b += v * att[64 + jj];
    }
    s1o[(size_t)g * K + i] = a;
    s2o[(size_t)g * K + i] = b;
    gidx[(size_t)g * K + i] = li;  // local index within old graph
    float* xout = xn + ((size_t)g * K + i) * 64;
    for (int jj = 0; jj < 64; ++jj) xout[jj] = xs[i * 64 + jj];
  }
  __syncthreads();
  if (i < 64) {
    float mx = -1e30f, sm = 0.f;
    for (int r = 0; r < K; ++r) { float v = xs[r * 64 + i]; mx = fmaxf(mx, v); sm += v; }
    xread[(size_t)g * 128 + i] = mx;
    xread[(size_t)g * 128 + 64 + i] = sm * (1.0f / K);
  }
}

// new_adj[g][i][j] = max(s1_i + s2_j, 0) + adj_old[g][sel_i][sel_j]   (relu(leaky_relu(e)) == relu(e); LAMB=1)
template <int NPGL>
__global__ void k_stageE(const float* __restrict__ s1, const float* __restrict__ s2,
                         const int* __restrict__ gidx, const float* __restrict__ adj_old,
                         float* __restrict__ adj_new) {
  constexpr int K = NPGL / 2;
  int idx = blockIdx.x * blockDim.x + threadIdx.x;
  if (idx >= 32 * K * K) return;
  int g = idx / (K * K);
  int r = idx - g * K * K;
  int ii = r / K, jj = r - ii * K;
  float e = s1[(size_t)g * K + ii] + s2[(size_t)g * K + jj];
  float v = fmaxf(e, 0.f) +
            adj_old[(((size_t)g * NPGL) + gidx[(size_t)g * K + ii]) * NPGL + gidx[(size_t)g * K + jj]];
  adj_new[(((size_t)g * K) + ii) * K + jj] = v;
}

// readout of t3 (64 rows per graph, no pooling)
__global__ void k_readout64(const float* __restrict__ t, float* __restrict__ xread) {
  const int g = blockIdx.x, j = threadIdx.x;  // 64
  float mx = -1e30f, sm = 0.f;
  for (int r = 0; r < 64; ++r) { float v = t[((size_t)g * 64 + r) * 64 + j]; mx = fmaxf(mx, v); sm += v; }
  xread[(size_t)g * 128 + j] = mx;
  xread[(size_t)g * 128 + 64 + j] = sm * (1.0f / 64.0f);
}

// final MLP head + log_softmax; one block per batch row
__global__ void k_mlp(const float* __restrict__ x1, const float* __restrict__ x2,
                      const float* __restrict__ x3, const float* __restrict__ lw1,
                      const float* __restrict__ lb1, const float* __restrict__ lw2,
                      const float* __restrict__ lb2, const float* __restrict__ lw3,
                      const float* __restrict__ lb3, float* __restrict__ out) {
  const int b = blockIdx.x, j = threadIdx.x;  // 64
  __shared__ float r[128];
  __shared__ float h1[64];
  __shared__ float h2[32];
  __shared__ float z[6];
  for (int t = j; t < 128; t += 64)
    r[t] = fmaxf(x1[(size_t)b * 128 + t], 0.f) + fmaxf(x2[(size_t)b * 128 + t], 0.f) +
           fmaxf(x3[(size_t)b * 128 + t], 0.f);
  __syncthreads();
  float acc = lb1[j];
  for (int t = 0; t < 128; ++t) acc += r[t] * lw1[(size_t)j * 128 + t];
  h1[j] = fmaxf(acc, 0.f);
  __syncthreads();
  if (j < 32) {
    float a = lb2[j];
    for (int t = 0; t < 64; ++t) a += h1[t] * lw2[(size_t)j * 64 + t];
    h2[j] = fmaxf(a, 0.f);
  }
  __syncthreads();
  if (j < 6) {
    float a = lb3[j];
    for (int t = 0; t < 32; ++t) a += h2[t] * lw3[(size_t)j * 32 + t];
    z[j] = a;
  }
  __syncthreads();
  if (j < 6) {
    float m = z[0];
    for (int c = 1; c < 6; ++c) m = fmaxf(m, z[c]);
    float se = 0.f;
    for (int c = 0; c < 6; ++c) se += expf(z[c] - m);
    out[(size_t)b * 6 + j] = z[j] - m - logf(se);
  }
}

extern "C" void kernel_launch(void* const* d_in, const int* in_sizes, int n_in,
                              void* d_out, int out_size, void* d_ws, size_t ws_size,
                              hipStream_t stream) {
  const float* x = (const float*)d_in[0];
  const int* ei = (const int*)d_in[1];
  const float* W1 = (const float*)d_in[2];
  const float* b1 = (const float*)d_in[3];
  const float* W2 = (const float*)d_in[4];
  const float* b2 = (const float*)d_in[5];
  const float* W3 = (const float*)d_in[6];
  const float* b3 = (const float*)d_in[7];
  const float* att1 = (const float*)d_in[8];
  const float* att2 = (const float*)d_in[9];
  const float* lw1 = (const float*)d_in[10];
  const float* lb1 = (const float*)d_in[11];
  const float* lw2 = (const float*)d_in[12];
  const float* lb2 = (const float*)d_in[13];
  const float* lw3 = (const float*)d_in[14];
  const float* lb3 = (const float*)d_in[15];
  float* out = (float*)d_out;
  const int nE = in_sizes[1] / 2;

  float* p = (float*)d_ws;
  float* srow = p;  p += 8192;
  float* adj1 = p;  p += (size_t)32 * 256 * 256;
  float* adj2 = p;  p += (size_t)32 * 128 * 128;
  float* adj3 = p;  p += (size_t)32 * 64 * 64;
  float* ubuf = p;  p += (size_t)8192 * 64;
  float* t1 = p;    p += (size_t)8192 * 64;
  float* t2 = p;    p += (size_t)4096 * 64;
  float* t3 = p;    p += (size_t)2048 * 64;
  float* dis = p;   p += 8192;
  float* score = p; p += 8192;
  float* xn1 = p;   p += (size_t)4096 * 64;
  float* xn2 = p;   p += (size_t)2048 * 64;
  float* s1b = p;   p += 4096;
  float* s2b = p;   p += 4096;
  float* x1 = p;    p += 32 * 128;
  float* x2 = p;    p += 32 * 128;
  float* x3 = p;    p += 32 * 128;
  int* gidx1 = (int*)p; p += 4096;
  int* gidx2 = (int*)p; p += 2048;

  hipMemsetAsync(adj1, 0, (size_t)32 * 256 * 256 * sizeof(float), stream);
  k_rowsum<<<8192, 64, 0, stream>>>(x, srow);
  k_edges<<<(nE + 255) / 256, 256, 0, stream>>>(ei, ei + nE, srow, adj1, nE);

  // layer 1 (N=8192, graph=256)
  k_stageA<128><<<8192, 64, 0, stream>>>(x, W1, b1, ubuf);
  k_stageB<256><<<8192, 64, 0, stream>>>(adj1, ubuf, t1, dis, 1);
  k_stageC<256><<<8192, 64, 0, stream>>>(adj1, t1, dis, score);
  k_stageD<256><<<32, 256, 0, stream>>>(score, t1, att1, xn1, s1b, s2b, gidx1, x1);
  k_stageE<256><<<(32 * 128 * 128 + 255) / 256, 256, 0, stream>>>(s1b, s2b, gidx1, adj1, adj2);

  // layer 2 (N=4096, graph=128)
  k_stageA<64><<<4096, 64, 0, stream>>>(xn1, W2, b2, ubuf);
  k_stageB<128><<<4096, 64, 0, stream>>>(adj2, ubuf, t2, dis, 1);
  k_stageC<128><<<4096, 64, 0, stream>>>(adj2, t2, dis, score);
  k_stageD<128><<<32, 128, 0, stream>>>(score, t2, att2, xn2, s1b, s2b, gidx2, x2);
  k_stageE<128><<<(32 * 64 * 64 + 255) / 256, 256, 0, stream>>>(s1b, s2b, gidx2, adj2, adj3);

  // layer 3 (N=2048, graph=64)
  k_stageA<64><<<2048, 64, 0, stream>>>(xn2, W3, b3, ubuf);
  k_stageB<64><<<2048, 64, 0, stream>>>(adj3, ubuf, t3, dis, 0);
  k_readout64<<<32, 64, 0, stream>>>(t3, x3);

  k_mlp<<<32, 64, 0, stream>>>(x1, x2, x3, lw1, lb1, lw2, lb2, lw3, lb3, out);
}